// Round 3
// baseline (2015.370 us; speedup 1.0000x reference)
//
#include <hip/hip_runtime.h>
#include <hip/hip_cooperative_groups.h>

namespace cg = cooperative_groups;

// Perona-Malik diffusion, 500 iterations in ONE cooperative kernel.
// 256 blocks (1/CU); each owns a 64x32 interior tile on an 88x52 LDS region
// (halo 12x10 >= T_FUSE=10). Coefficients gathered into registers ONCE;
// 50 supersteps of 10 LDS-ping-pong Jacobi steps, grid.sync() between them.
// Interior values persist in registers across supersteps; only the halo ring
// is re-read from the global ping-pong buffers.

#define HH 512
#define WW 512
#define NB 2
static constexpr float LAM   = 0.24f;
static constexpr float KCOND = 0.03f;
static constexpr float DEPS_ = 0.1f;
static constexpr int IMG      = HH * WW;
static constexpr int N_DEPTH  = NB * IMG;
static constexpr int CV_PER_B = (HH - 1) * WW;   // 261632
static constexpr int CH_PER_B = HH * (WW - 1);   // 261632
static constexpr int N_CV     = NB * CV_PER_B;
static constexpr int N_CH     = NB * CH_PER_B;

static constexpr int T_FUSE = 10;
static constexpr int NSS    = 50;                 // 50 x 10 = 500
static constexpr int TILE_W = 64, TILE_H = 32;
static constexpr int HALO_X = 12, HALO_Y = 10;
static constexpr int RW = TILE_W + 2 * HALO_X;    // 88
static constexpr int RH = TILE_H + 2 * HALO_Y;    // 52
static constexpr int NQ_ROW = RW / 4;             // 22
static constexpr int NQUAD  = NQ_ROW * RH;        // 1144
static constexpr int QPT    = (NQUAD + 255) / 256; // 5
static constexpr int SSZ    = (RH + 2) * RW;      // + top/bottom guard rows

// ---- monotone float<->uint key for atomic min ----
__device__ __forceinline__ unsigned fkey(float f) {
    unsigned u = __float_as_uint(f);
    return (u & 0x80000000u) ? ~u : (u | 0x80000000u);
}
__device__ __forceinline__ float kinv(unsigned k) {
    return __uint_as_float((k & 0x80000000u) ? (k & 0x7fffffffu) : ~k);
}

__global__ void init_key_kernel(unsigned* key) { *key = 0xFFFFFFFFu; }

__global__ void min_kernel(const float* __restrict__ x, unsigned* key) {
    float m = 3.4e38f;
    for (int idx = blockIdx.x * blockDim.x + threadIdx.x; idx < N_DEPTH;
         idx += gridDim.x * blockDim.x)
        m = fminf(m, x[idx]);
    for (int off = 32; off > 0; off >>= 1) m = fminf(m, __shfl_down(m, off, 64));
    __shared__ float sm[4];
    int lane = threadIdx.x & 63, wv = threadIdx.x >> 6;
    if (lane == 0) sm[wv] = m;
    __syncthreads();
    if (threadIdx.x == 0) {
        float mm = fminf(fminf(sm[0], sm[1]), fminf(sm[2], sm[3]));
        atomicMin(key, fkey(mm));
    }
}

__global__ void coeff_kernel(const float* __restrict__ g, float* __restrict__ cv,
                             float* __restrict__ chh) {
    int idx = blockIdx.x * blockDim.x + threadIdx.x;
    constexpr float kk = KCOND * KCOND;
    if (idx < N_CV) {
        int b = idx / CV_PER_B;
        int r = idx - b * CV_PER_B;
        int i = r >> 9, j = r & (WW - 1);
        const float* gb = g + b * 3 * IMG + i * WW + j;
        float s = 0.f;
#pragma unroll
        for (int c = 0; c < 3; ++c) s += fabsf(gb[c * IMG + WW] - gb[c * IMG]);
        float m = s / 3.0f;
        cv[idx] = 1.0f / (1.0f + (m * m) / kk);
    } else if (idx < N_CV + N_CH) {
        int t = idx - N_CV;
        int b = t / CH_PER_B;
        int r = t - b * CH_PER_B;
        int i = r / (WW - 1);
        int j = r - i * (WW - 1);
        const float* gb = g + b * 3 * IMG + i * WW + j;
        float s = 0.f;
#pragma unroll
        for (int c = 0; c < 3; ++c) s += fabsf(gb[c * IMG + 1] - gb[c * IMG]);
        float m = s / 3.0f;
        chh[t] = 1.0f / (1.0f + (m * m) / kk);
    }
}

__global__ __launch_bounds__(256, 1) void diffuse_coop(
    const float* __restrict__ initial, const float* __restrict__ cv_g,
    const float* __restrict__ ch_g, float* __restrict__ bufA,
    float* __restrict__ bufB, float* __restrict__ out_y,
    const unsigned* __restrict__ key) {
    cg::grid_group grid = cg::this_grid();
    __shared__ float sb[2][SSZ];

    const int blk = blockIdx.x;
    const int b   = blk >> 7;
    const int t   = blk & 127;             // 16 tile-rows x 8 tile-cols
    const int y0  = (t >> 3) * TILE_H;
    const int x0  = (t & 7) * TILE_W;
    const float* cvb   = cv_g + b * CV_PER_B;
    const float* chb   = ch_g + b * CH_PER_B;
    const float* ini_b = initial + b * IMG;

    const float shift = (kinv(*key) <= DEPS_) ? DEPS_ : 0.f;
    const int tid = threadIdx.x;

    float v[QPT][4];
    float cu[QPT][4], cd[QPT][4], chq[QPT][5];
    int   roff[QPT], goff[QPT];
    bool  act[QPT], in_img[QPT], is_int[QPT];

    // ---- one-time setup: geometry + coefficient gather into registers ----
#pragma unroll
    for (int q = 0; q < QPT; ++q) {
        int qi = tid + q * 256;
        act[q] = qi < NQUAD;
        int qc = act[q] ? qi : 0;
        int r  = qc / NQ_ROW;
        int x  = (qc - r * NQ_ROW) * 4;
        roff[q] = (r + 1) * RW + x;        // +1: top guard row
        int gy = y0 - HALO_Y + r;
        int gx = x0 - HALO_X + x;
        bool gy_in  = (gy >= 0) && (gy < HH);
        bool gx_in4 = (gx >= 0) && (gx <= WW - 4);  // gx is a multiple of 4
        in_img[q] = act[q] && gy_in && gx_in4;
        goff[q]   = in_img[q] ? (gy * WW + gx) : 0;
        is_int[q] = act[q] && (r >= HALO_Y) && (r < HALO_Y + TILE_H) &&
                    (x >= HALO_X) && (x < HALO_X + TILE_W);
#pragma unroll
        for (int j = 0; j < 4; ++j) {
            v[q][j] = 0.f;
            int  gxx   = gx + j;
            bool gx_in = (gxx >= 0) && (gxx < WW);
            bool up_ok = act[q] && (r >= 1) && (gy >= 1) && (gy < HH) && gx_in;
            cu[q][j] = up_ok ? LAM * cvb[(gy - 1) * WW + gxx] : 0.f;
            bool dn_ok = act[q] && (r <= RH - 2) && (gy >= 0) && (gy < HH - 1) && gx_in;
            cd[q][j] = dn_ok ? LAM * cvb[gy * WW + gxx] : 0.f;
        }
#pragma unroll
        for (int jj = 0; jj < 5; ++jj) {
            int  xe  = x + jj;
            int  gxe = gx + jj;
            bool ok = act[q] && (xe >= 1) && (xe <= RW - 1) && gy_in &&
                      (gxe >= 1) && (gxe < WW);
            chq[q][jj] = ok ? LAM * chb[gy * (WW - 1) + (gxe - 1)] : 0.f;
        }
    }

    // zero guard rows of both LDS buffers (never written again)
    for (int i = tid; i < RW; i += 256) {
        sb[0][i] = 0.f; sb[0][(RH + 1) * RW + i] = 0.f;
        sb[1][i] = 0.f; sb[1][(RH + 1) * RW + i] = 0.f;
    }

#pragma unroll 1
    for (int ss = 0; ss < NSS; ++ss) {
        const bool first = (ss == 0), last = (ss == NSS - 1);
        const float* srcb =
            (first ? ini_b : (((ss & 1) ? bufA : bufB) + b * IMG));

        // refresh halo ring (interior quads keep their register values)
#pragma unroll
        for (int q = 0; q < QPT; ++q) {
            if (in_img[q] && (first || !is_int[q])) {
                float4 tv = *reinterpret_cast<const float4*>(srcb + goff[q]);
                if (first) { tv.x += shift; tv.y += shift; tv.z += shift; tv.w += shift; }
                v[q][0] = tv.x; v[q][1] = tv.y; v[q][2] = tv.z; v[q][3] = tv.w;
            }
        }
#pragma unroll
        for (int q = 0; q < QPT; ++q)
            if (act[q])
                *reinterpret_cast<float4*>(&sb[0][roff[q]]) =
                    float4{v[q][0], v[q][1], v[q][2], v[q][3]};
        __syncthreads();

        int cur = 0;
        for (int it = 0; it < T_FUSE; ++it) {
            float nv[QPT][4];
#pragma unroll
            for (int q = 0; q < QPT; ++q) {
                const float* s = sb[cur];
                float4 up = *reinterpret_cast<const float4*>(&s[roff[q] - RW]);
                float4 dn = *reinterpret_cast<const float4*>(&s[roff[q] + RW]);
                float  lf = s[roff[q] - 1];
                float  rt = s[roff[q] + 4];
                float c0 = v[q][0], c1 = v[q][1], c2 = v[q][2], c3 = v[q][3];
                nv[q][0] = c0 - cu[q][0] * (c0 - up.x) + cd[q][0] * (dn.x - c0)
                              - chq[q][0] * (c0 - lf) + chq[q][1] * (c1 - c0);
                nv[q][1] = c1 - cu[q][1] * (c1 - up.y) + cd[q][1] * (dn.y - c1)
                              - chq[q][1] * (c1 - c0) + chq[q][2] * (c2 - c1);
                nv[q][2] = c2 - cu[q][2] * (c2 - up.z) + cd[q][2] * (dn.z - c2)
                              - chq[q][2] * (c2 - c1) + chq[q][3] * (c3 - c2);
                nv[q][3] = c3 - cu[q][3] * (c3 - up.w) + cd[q][3] * (dn.w - c3)
                              - chq[q][3] * (c3 - c2) + chq[q][4] * (rt - c3);
            }
            int nxt = cur ^ 1;
#pragma unroll
            for (int q = 0; q < QPT; ++q) {
                if (act[q])
                    *reinterpret_cast<float4*>(&sb[nxt][roff[q]]) =
                        float4{nv[q][0], nv[q][1], nv[q][2], nv[q][3]};
                v[q][0] = nv[q][0]; v[q][1] = nv[q][1];
                v[q][2] = nv[q][2]; v[q][3] = nv[q][3];
            }
            cur = nxt;
            __syncthreads();
        }

        // store interior (exact after T_FUSE steps)
        float* dstb = (last ? out_y : ((ss & 1) ? bufB : bufA)) + b * IMG;
#pragma unroll
        for (int q = 0; q < QPT; ++q) {
            if (is_int[q]) {
                float4 o{v[q][0], v[q][1], v[q][2], v[q][3]};
                if (last) { o.x -= shift; o.y -= shift; o.z -= shift; o.w -= shift; }
                *reinterpret_cast<float4*>(dstb + goff[q]) = o;
            }
        }
        if (!last) grid.sync();
    }
}

extern "C" void kernel_launch(void* const* d_in, const int* in_sizes, int n_in,
                              void* d_out, int out_size, void* d_ws, size_t ws_size,
                              hipStream_t stream) {
    const float* guide   = (const float*)d_in[0];
    const float* initial = (const float*)d_in[1];
    float* out    = (float*)d_out;
    float* out_y  = out;
    float* out_cv = out + N_DEPTH;
    float* out_ch = out + N_DEPTH + N_CV;

    unsigned* key = (unsigned*)d_ws;
    float* wsf    = (float*)d_ws;
    float* bufA   = wsf + 64;
    float* bufB   = bufA + N_DEPTH;

    hipLaunchKernelGGL(init_key_kernel, dim3(1), dim3(1), 0, stream, key);
    hipLaunchKernelGGL(min_kernel, dim3(256), dim3(256), 0, stream, initial, key);

    int nco = N_CV + N_CH;
    hipLaunchKernelGGL(coeff_kernel, dim3((nco + 255) / 256), dim3(256), 0, stream,
                       guide, out_cv, out_ch);

    void* args[] = {(void*)&initial, (void*)&out_cv, (void*)&out_ch,
                    (void*)&bufA,    (void*)&bufB,   (void*)&out_y, (void*)&key};
    hipLaunchCooperativeKernel((void*)diffuse_coop, dim3(NB * 128), dim3(256),
                               args, 0, stream);
}

// Round 4
// 520.073 us; speedup vs baseline: 3.8752x; 3.8752x over previous
//
#include <hip/hip_runtime.h>

// Perona-Malik diffusion, 500 iters = 50 launches x 10 LDS-fused steps.
// Round-4 changes vs round 2: (a) one-time prep kernel bakes all boundary-
// predicated L*cv / L*ch coefficients into dense per-block planes in d_ws,
// so each step launch loads coeffs as coalesced float4s (no gathers, no
// divisions); (b) 512 threads/block (2 waves/SIMD) and QPT=3 to kill the
// register-spill / gather-sunk-into-loop problem seen in round 3 (VGPR=88).
// grid.sync() abandoned: measured ~30+ us/superstep; relaunch is ~2 us.

#define HH 512
#define WW 512
#define NB 2
static constexpr float LAM   = 0.24f;
static constexpr float KCOND = 0.03f;
static constexpr float DEPS_ = 0.1f;
static constexpr int IMG      = HH * WW;
static constexpr int N_DEPTH  = NB * IMG;
static constexpr int CV_PER_B = (HH - 1) * WW;
static constexpr int CH_PER_B = HH * (WW - 1);
static constexpr int N_CV     = NB * CV_PER_B;
static constexpr int N_CH     = NB * CH_PER_B;

static constexpr int T_FUSE = 10, NSS = 50;       // 50 x 10 = 500
static constexpr int TILE_W = 64, TILE_H = 32;
static constexpr int HALO_X = 12, HALO_Y = 10;
static constexpr int RW = TILE_W + 2 * HALO_X;    // 88
static constexpr int RH = TILE_H + 2 * HALO_Y;    // 52
static constexpr int NQ_ROW = RW / 4;             // 22
static constexpr int NQUAD  = NQ_ROW * RH;        // 1144
static constexpr int SSZ    = (RH + 2) * RW;      // +guard rows

// fast path: 512 threads, 3 quads/thread
static constexpr int NT  = 512;
static constexpr int QPT = 3;                      // ceil(1144/512)
// coefficient planes (per block): CV rows 0..RH (edge above region row r),
// CH row width padded to 96 so the 5-edge read is aligned f4 + scalar.
static constexpr int CVW = RW;                     // 88
static constexpr int CV_SZ = (RH + 1) * CVW;       // 4664
static constexpr int CHW = RW + 8;                 // 96
static constexpr int CH_SZ = RH * CHW;             // 4992
static constexpr int BLOB_BLK = CV_SZ + CH_SZ;     // 9656 floats/block

// fallback path (round-2 verified): 256 threads, 5 quads/thread
static constexpr int QPT_F = 5;

// ---- monotone float<->uint key for atomic min ----
__device__ __forceinline__ unsigned fkey(float f) {
    unsigned u = __float_as_uint(f);
    return (u & 0x80000000u) ? ~u : (u | 0x80000000u);
}
__device__ __forceinline__ float kinv(unsigned k) {
    return __uint_as_float((k & 0x80000000u) ? (k & 0x7fffffffu) : ~k);
}

__global__ void init_key_kernel(unsigned* key) { *key = 0xFFFFFFFFu; }

__global__ void min_kernel(const float* __restrict__ x, unsigned* key) {
    float m = 3.4e38f;
    for (int idx = blockIdx.x * blockDim.x + threadIdx.x; idx < N_DEPTH;
         idx += gridDim.x * blockDim.x)
        m = fminf(m, x[idx]);
    for (int off = 32; off > 0; off >>= 1) m = fminf(m, __shfl_down(m, off, 64));
    __shared__ float sm[4];
    int lane = threadIdx.x & 63, wv = threadIdx.x >> 6;
    if (lane == 0) sm[wv] = m;
    __syncthreads();
    if (threadIdx.x == 0) {
        float mm = fminf(fminf(sm[0], sm[1]), fminf(sm[2], sm[3]));
        atomicMin(key, fkey(mm));
    }
}

__global__ void coeff_kernel(const float* __restrict__ g, float* __restrict__ cv,
                             float* __restrict__ chh) {
    int idx = blockIdx.x * blockDim.x + threadIdx.x;
    constexpr float kk = KCOND * KCOND;
    if (idx < N_CV) {
        int b = idx / CV_PER_B;
        int r = idx - b * CV_PER_B;
        int i = r >> 9, j = r & (WW - 1);
        const float* gb = g + b * 3 * IMG + i * WW + j;
        float s = 0.f;
#pragma unroll
        for (int c = 0; c < 3; ++c) s += fabsf(gb[c * IMG + WW] - gb[c * IMG]);
        float m = s / 3.0f;
        cv[idx] = 1.0f / (1.0f + (m * m) / kk);
    } else if (idx < N_CV + N_CH) {
        int t = idx - N_CV;
        int b = t / CH_PER_B;
        int r = t - b * CH_PER_B;
        int i = r / (WW - 1);
        int j = r - i * (WW - 1);
        const float* gb = g + b * 3 * IMG + i * WW + j;
        float s = 0.f;
#pragma unroll
        for (int c = 0; c < 3; ++c) s += fabsf(gb[c * IMG + 1] - gb[c * IMG]);
        float m = s / 3.0f;
        chh[t] = 1.0f / (1.0f + (m * m) / kk);
    }
}

// One-time: bake predicated L*cv / L*ch into dense per-block planes.
// CV[rr][x] = coeff of vertical edge ABOVE region row rr (0 where invalid):
//   cu(quad row r) = CV[r], cd(quad row r) = CV[r+1].
// CH[rr][xe] = coeff of horizontal edge whose RIGHT pixel is region col xe.
__global__ __launch_bounds__(256) void prep_planes(const float* __restrict__ cv_g,
                                                   const float* __restrict__ ch_g,
                                                   float* __restrict__ blob) {
    const int blk = blockIdx.x;
    const int b   = blk >> 7, t = blk & 127;
    const int y0  = (t >> 3) * TILE_H;
    const int x0  = (t & 7) * TILE_W;
    const float* cvb = cv_g + b * CV_PER_B;
    const float* chb = ch_g + b * CH_PER_B;
    float* pv = blob + blk * BLOB_BLK;
    float* ph = pv + CV_SZ;
    for (int i = threadIdx.x; i < CV_SZ; i += 256) {
        int rr = i / CVW, x = i - rr * CVW;
        int gy = y0 - HALO_Y + rr, gx = x0 - HALO_X + x;
        bool ok = (rr >= 1) && (rr <= RH - 1) && (gy >= 1) && (gy <= HH - 1) &&
                  (gx >= 0) && (gx < WW);
        pv[i] = ok ? LAM * cvb[(gy - 1) * WW + gx] : 0.f;
    }
    for (int i = threadIdx.x; i < CH_SZ; i += 256) {
        int rr = i / CHW, xe = i - rr * CHW;
        int gy = y0 - HALO_Y + rr, gxe = x0 - HALO_X + xe;
        bool ok = (xe >= 1) && (xe <= RW - 1) && (gy >= 0) && (gy < HH) &&
                  (gxe >= 1) && (gxe < WW);
        ph[i] = ok ? LAM * chb[gy * (WW - 1) + (gxe - 1)] : 0.f;
    }
}

template <bool ADD_SHIFT, bool SUB_SHIFT>
__global__ __launch_bounds__(NT, 1) void step_fast(
    const float* __restrict__ src, float* __restrict__ dst,
    const float* __restrict__ blob, const unsigned* __restrict__ key) {
    __shared__ float sb[2][SSZ];
    const int blk = blockIdx.x;
    const int b   = blk >> 7, t = blk & 127;
    const int y0  = (t >> 3) * TILE_H;
    const int x0  = (t & 7) * TILE_W;
    const float* srcb = src + b * IMG;
    const float* pv   = blob + blk * BLOB_BLK;
    const float* ph   = pv + CV_SZ;

    float shift = 0.f;
    if (ADD_SHIFT || SUB_SHIFT) shift = (kinv(*key) <= DEPS_) ? DEPS_ : 0.f;
    const int tid = threadIdx.x;

    float v[QPT][4], cu[QPT][4], cd[QPT][4], chq[QPT][5];
    int   roff[QPT], goff[QPT];
    bool  is_int[QPT], in_img[QPT];

#pragma unroll
    for (int q = 0; q < QPT; ++q) {
        int qi   = tid + q * NT;
        bool act = qi < NQUAD;
        int qc   = act ? qi : 0;
        int r    = qc / NQ_ROW;
        int x    = (qc - r * NQ_ROW) * 4;
        roff[q]  = (r + 1) * RW + x;
        int gy = y0 - HALO_Y + r, gx = x0 - HALO_X + x;
        bool gy_in = (gy >= 0) && (gy < HH);
        in_img[q]  = act && gy_in && (gx >= 0) && (gx <= WW - 4);
        goff[q]    = in_img[q] ? (gy * WW + gx) : 0;
        is_int[q]  = act && (r >= HALO_Y) && (r < HALO_Y + TILE_H) &&
                     (x >= HALO_X) && (x < HALO_X + TILE_W);
        float4 a  = *reinterpret_cast<const float4*>(&pv[r * CVW + x]);
        float4 d  = *reinterpret_cast<const float4*>(&pv[(r + 1) * CVW + x]);
        float4 h  = *reinterpret_cast<const float4*>(&ph[r * CHW + x]);
        float  h4 = ph[r * CHW + x + 4];
        float am = act ? 1.f : 0.f;
        cu[q][0] = a.x * am; cu[q][1] = a.y * am; cu[q][2] = a.z * am; cu[q][3] = a.w * am;
        cd[q][0] = d.x * am; cd[q][1] = d.y * am; cd[q][2] = d.z * am; cd[q][3] = d.w * am;
        chq[q][0] = h.x * am; chq[q][1] = h.y * am; chq[q][2] = h.z * am;
        chq[q][3] = h.w * am; chq[q][4] = h4 * am;
        float4 tv = {0.f, 0.f, 0.f, 0.f};
        if (in_img[q]) tv = *reinterpret_cast<const float4*>(srcb + goff[q]);
        if (ADD_SHIFT && in_img[q]) {
            tv.x += shift; tv.y += shift; tv.z += shift; tv.w += shift;
        }
        v[q][0] = tv.x; v[q][1] = tv.y; v[q][2] = tv.z; v[q][3] = tv.w;
    }

    for (int i = tid; i < RW; i += NT) {
        sb[0][i] = 0.f; sb[0][(RH + 1) * RW + i] = 0.f;
        sb[1][i] = 0.f; sb[1][(RH + 1) * RW + i] = 0.f;
    }
#pragma unroll
    for (int q = 0; q < QPT; ++q)
        *reinterpret_cast<float4*>(&sb[0][roff[q]]) =
            float4{v[q][0], v[q][1], v[q][2], v[q][3]};
    __syncthreads();

    int cur = 0;
    for (int it = 0; it < T_FUSE; ++it) {
        float nv[QPT][4];
#pragma unroll
        for (int q = 0; q < QPT; ++q) {
            const float* s = sb[cur];
            float4 up = *reinterpret_cast<const float4*>(&s[roff[q] - RW]);
            float4 dn = *reinterpret_cast<const float4*>(&s[roff[q] + RW]);
            float  lf = s[roff[q] - 1];
            float  rt = s[roff[q] + 4];
            float c0 = v[q][0], c1 = v[q][1], c2 = v[q][2], c3 = v[q][3];
            nv[q][0] = c0 - cu[q][0] * (c0 - up.x) + cd[q][0] * (dn.x - c0)
                          - chq[q][0] * (c0 - lf) + chq[q][1] * (c1 - c0);
            nv[q][1] = c1 - cu[q][1] * (c1 - up.y) + cd[q][1] * (dn.y - c1)
                          - chq[q][1] * (c1 - c0) + chq[q][2] * (c2 - c1);
            nv[q][2] = c2 - cu[q][2] * (c2 - up.z) + cd[q][2] * (dn.z - c2)
                          - chq[q][2] * (c2 - c1) + chq[q][3] * (c3 - c2);
            nv[q][3] = c3 - cu[q][3] * (c3 - up.w) + cd[q][3] * (dn.w - c3)
                          - chq[q][3] * (c3 - c2) + chq[q][4] * (rt - c3);
        }
        int nxt = cur ^ 1;
#pragma unroll
        for (int q = 0; q < QPT; ++q) {
            *reinterpret_cast<float4*>(&sb[nxt][roff[q]]) =
                float4{nv[q][0], nv[q][1], nv[q][2], nv[q][3]};
            v[q][0] = nv[q][0]; v[q][1] = nv[q][1];
            v[q][2] = nv[q][2]; v[q][3] = nv[q][3];
        }
        cur = nxt;
        __syncthreads();
    }

    float* dstb = dst + b * IMG;
#pragma unroll
    for (int q = 0; q < QPT; ++q) {
        if (is_int[q]) {
            float4 o{v[q][0], v[q][1], v[q][2], v[q][3]};
            if (SUB_SHIFT) { o.x -= shift; o.y -= shift; o.z -= shift; o.w -= shift; }
            *reinterpret_cast<float4*>(dstb + goff[q]) = o;
        }
    }
}

// -------- fallback (round-2 verified, inline gather, 256 threads) --------
template <bool ADD_SHIFT, bool SUB_SHIFT>
__global__ __launch_bounds__(256, 1) void step_fused(
    const float* __restrict__ src, float* __restrict__ dst,
    const float* __restrict__ cv_g, const float* __restrict__ ch_g,
    const unsigned* __restrict__ key) {
    __shared__ float sb[2][SSZ];
    const int blk = blockIdx.x;
    const int b = blk >> 7, t = blk & 127;
    const int y0 = (t >> 3) * TILE_H, x0 = (t & 7) * TILE_W;
    const float* cvb = cv_g + b * CV_PER_B;
    const float* chb = ch_g + b * CH_PER_B;
    const float* srcb = src + b * IMG;
    float* dstb = dst + b * IMG;
    float shift = 0.f;
    if (ADD_SHIFT || SUB_SHIFT) shift = (kinv(*key) <= DEPS_) ? DEPS_ : 0.f;
    const int tid = threadIdx.x;
    float v[QPT_F][4], cu[QPT_F][4], cd[QPT_F][4], chq[QPT_F][5];
    int roff[QPT_F], rr[QPT_F], xx[QPT_F];
    bool act[QPT_F];
#pragma unroll
    for (int q = 0; q < QPT_F; ++q) {
        int qi = tid + q * 256;
        act[q] = qi < NQUAD;
        int qc = act[q] ? qi : 0;
        int r = qc / NQ_ROW;
        int x = (qc - r * NQ_ROW) * 4;
        rr[q] = r; xx[q] = x;
        roff[q] = (r + 1) * RW + x;
        int gy = y0 - HALO_Y + r, gx = x0 - HALO_X + x;
        bool gy_in = (gy >= 0) && (gy < HH);
#pragma unroll
        for (int j = 0; j < 4; ++j) {
            int gxx = gx + j;
            bool gx_in = (gxx >= 0) && (gxx < WW);
            bool vin = act[q] && gy_in && gx_in;
            float val = vin ? srcb[gy * WW + gxx] : 0.f;
            if (ADD_SHIFT) val += shift;
            v[q][j] = vin ? val : 0.f;
            bool up_ok = act[q] && (r >= 1) && (gy >= 1) && (gy < HH) && gx_in;
            cu[q][j] = up_ok ? LAM * cvb[(gy - 1) * WW + gxx] : 0.f;
            bool dn_ok = act[q] && (r <= RH - 2) && (gy >= 0) && (gy < HH - 1) && gx_in;
            cd[q][j] = dn_ok ? LAM * cvb[gy * WW + gxx] : 0.f;
        }
#pragma unroll
        for (int jj = 0; jj < 5; ++jj) {
            int xe = x + jj, gxe = gx + jj;
            bool ok = act[q] && (xe >= 1) && (xe <= RW - 1) && gy_in &&
                      (gxe >= 1) && (gxe < WW);
            chq[q][jj] = ok ? LAM * chb[gy * (WW - 1) + (gxe - 1)] : 0.f;
        }
    }
    for (int i = tid; i < RW; i += 256) {
        sb[0][i] = 0.f; sb[0][(RH + 1) * RW + i] = 0.f;
        sb[1][i] = 0.f; sb[1][(RH + 1) * RW + i] = 0.f;
    }
#pragma unroll
    for (int q = 0; q < QPT_F; ++q)
        if (act[q])
            *reinterpret_cast<float4*>(&sb[0][roff[q]]) =
                float4{v[q][0], v[q][1], v[q][2], v[q][3]};
    __syncthreads();
    int cur = 0;
    for (int it = 0; it < T_FUSE; ++it) {
        float nv[QPT_F][4];
#pragma unroll
        for (int q = 0; q < QPT_F; ++q) {
            const float* s = sb[cur];
            float4 up = *reinterpret_cast<const float4*>(&s[roff[q] - RW]);
            float4 dn = *reinterpret_cast<const float4*>(&s[roff[q] + RW]);
            float lf = s[roff[q] - 1];
            float rt = s[roff[q] + 4];
            float c0 = v[q][0], c1 = v[q][1], c2 = v[q][2], c3 = v[q][3];
            nv[q][0] = c0 - cu[q][0] * (c0 - up.x) + cd[q][0] * (dn.x - c0)
                          - chq[q][0] * (c0 - lf) + chq[q][1] * (c1 - c0);
            nv[q][1] = c1 - cu[q][1] * (c1 - up.y) + cd[q][1] * (dn.y - c1)
                          - chq[q][1] * (c1 - c0) + chq[q][2] * (c2 - c1);
            nv[q][2] = c2 - cu[q][2] * (c2 - up.z) + cd[q][2] * (dn.z - c2)
                          - chq[q][2] * (c2 - c1) + chq[q][3] * (c3 - c2);
            nv[q][3] = c3 - cu[q][3] * (c3 - up.w) + cd[q][3] * (dn.w - c3)
                          - chq[q][3] * (c3 - c2) + chq[q][4] * (rt - c3);
        }
        int nxt = cur ^ 1;
#pragma unroll
        for (int q = 0; q < QPT_F; ++q) {
            if (act[q])
                *reinterpret_cast<float4*>(&sb[nxt][roff[q]]) =
                    float4{nv[q][0], nv[q][1], nv[q][2], nv[q][3]};
            v[q][0] = nv[q][0]; v[q][1] = nv[q][1];
            v[q][2] = nv[q][2]; v[q][3] = nv[q][3];
        }
        cur = nxt;
        __syncthreads();
    }
#pragma unroll
    for (int q = 0; q < QPT_F; ++q) {
        if (!act[q]) continue;
        int r = rr[q], x = xx[q];
        if (r >= HALO_Y && r < HALO_Y + TILE_H && x >= HALO_X && x < HALO_X + TILE_W) {
            int gy = y0 - HALO_Y + r, gx = x0 - HALO_X + x;
            float4 o{v[q][0], v[q][1], v[q][2], v[q][3]};
            if (SUB_SHIFT) { o.x -= shift; o.y -= shift; o.z -= shift; o.w -= shift; }
            *reinterpret_cast<float4*>(dstb + gy * WW + gx) = o;
        }
    }
}

extern "C" void kernel_launch(void* const* d_in, const int* in_sizes, int n_in,
                              void* d_out, int out_size, void* d_ws, size_t ws_size,
                              hipStream_t stream) {
    const float* guide   = (const float*)d_in[0];
    const float* initial = (const float*)d_in[1];
    float* out    = (float*)d_out;
    float* out_y  = out;
    float* out_cv = out + N_DEPTH;
    float* out_ch = out + N_DEPTH + N_CV;

    unsigned* key = (unsigned*)d_ws;
    float* wsf    = (float*)d_ws;
    float* bufA   = wsf + 64;
    float* bufB   = bufA + N_DEPTH;
    float* blob   = bufB + N_DEPTH;

    const size_t need = (size_t)(64 + 2 * N_DEPTH + 256 * BLOB_BLK) * 4;
    const bool fast = ws_size >= need;

    hipLaunchKernelGGL(init_key_kernel, dim3(1), dim3(1), 0, stream, key);
    hipLaunchKernelGGL(min_kernel, dim3(256), dim3(256), 0, stream, initial, key);

    int nco = N_CV + N_CH;
    hipLaunchKernelGGL(coeff_kernel, dim3((nco + 255) / 256), dim3(256), 0, stream,
                       guide, out_cv, out_ch);
    if (fast)
        hipLaunchKernelGGL(prep_planes, dim3(256), dim3(256), 0, stream,
                           out_cv, out_ch, blob);

    float* bufs[2] = {bufA, bufB};
    for (int k = 0; k < NSS; ++k) {
        const float* src = (k == 0) ? initial : bufs[(k + 1) & 1];
        float*       dst = (k == NSS - 1) ? out_y : bufs[k & 1];
        if (fast) {
            if (k == 0)
                hipLaunchKernelGGL((step_fast<true, false>), dim3(256), dim3(NT), 0,
                                   stream, src, dst, blob, key);
            else if (k == NSS - 1)
                hipLaunchKernelGGL((step_fast<false, true>), dim3(256), dim3(NT), 0,
                                   stream, src, dst, blob, key);
            else
                hipLaunchKernelGGL((step_fast<false, false>), dim3(256), dim3(NT), 0,
                                   stream, src, dst, blob, key);
        } else {
            if (k == 0)
                hipLaunchKernelGGL((step_fused<true, false>), dim3(256), dim3(256), 0,
                                   stream, src, dst, out_cv, out_ch, key);
            else if (k == NSS - 1)
                hipLaunchKernelGGL((step_fused<false, true>), dim3(256), dim3(256), 0,
                                   stream, src, dst, out_cv, out_ch, key);
            else
                hipLaunchKernelGGL((step_fused<false, false>), dim3(256), dim3(256), 0,
                                   stream, src, dst, out_cv, out_ch, key);
        }
    }
}